// Round 1
// baseline (385.544 us; speedup 1.0000x reference)
//
#include <hip/hip_runtime.h>
#include <stdint.h>

// Problem constants
#define B_   32
#define T_   2048
#define E_   256
#define H_   256
#define LBL_ 20
#define M_   (B_ * T_)      // 65536 rows
#define NPACK_ 1536         // 2 dirs * 3 gates (i,g,o) * 256

typedef __attribute__((ext_vector_type(8))) short bf16x8;
typedef __attribute__((ext_vector_type(4))) float f32x4;

__device__ __forceinline__ unsigned short f2bf(float f) {
    union { float f; unsigned int u; } a; a.f = f;
    unsigned int u = a.u;
    u += 0x7FFFu + ((u >> 16) & 1u);   // RNE
    return (unsigned short)(u >> 16);
}

__device__ __forceinline__ float rcp_(float x) {
#if __has_builtin(__builtin_amdgcn_rcpf)
    return __builtin_amdgcn_rcpf(x);
#else
    return 1.0f / x;
#endif
}
__device__ __forceinline__ float sigm_(float x) {
    x = fminf(fmaxf(x, -30.f), 30.f);
    return rcp_(1.f + __expf(-x));
}
__device__ __forceinline__ float tanh_(float x) {
    x = fminf(fmaxf(x, -15.f), 15.f);
    float e = __expf(-2.f * x);
    return (1.f - e) * rcp_(1.f + e);
}

// ---------- kernel 1: cast X fp32 -> bf16 (8 elems / thread) ----------
__global__ __launch_bounds__(256) void cast_x(const float4* __restrict__ X4,
                                              uint4* __restrict__ Xb4) {
    int idx = blockIdx.x * 256 + threadIdx.x;
    float4 v0 = X4[2 * idx], v1 = X4[2 * idx + 1];
    union { unsigned short us[8]; uint4 u; } r;
    r.us[0] = f2bf(v0.x); r.us[1] = f2bf(v0.y); r.us[2] = f2bf(v0.z); r.us[3] = f2bf(v0.w);
    r.us[4] = f2bf(v1.x); r.us[5] = f2bf(v1.y); r.us[6] = f2bf(v1.z); r.us[7] = f2bf(v1.w);
    Xb4[idx] = r.u;
}

// ---------- kernel 2: pack weights ----------
// Wp row n: gidx = n/48 (dir = gidx>>4, c16 = gidx&15), r = n%48, ty = r/16 in {i,g,o},
// cc = r%16 -> source gate row = {0,2,3}[ty]*256 + c16*16 + cc.  (f gate dead: c0 == 0)
__global__ __launch_bounds__(256) void pack_w(
    const float* __restrict__ Wf, const float* __restrict__ bif, const float* __restrict__ bhf,
    const float* __restrict__ Wr, const float* __restrict__ bir, const float* __restrict__ bhr,
    unsigned short* __restrict__ Wp, float* __restrict__ bias_p)
{
    int n = blockIdx.x, t = threadIdx.x;
    int gidx = n / 48, r = n % 48;
    int ty = r >> 4, cc = r & 15;
    int dir = gidx >> 4, c = (gidx & 15) * 16 + cc;
    int gate = (ty == 0) ? 0 : (ty == 1 ? 2 : 3);
    int wrow = gate * 256 + c;
    const float* W = dir ? Wr : Wf;
    Wp[n * 256 + t] = f2bf(W[wrow * 256 + t]);
    if (t == 0)
        bias_p[n] = (dir ? bir[wrow] : bif[wrow]) + (dir ? bhr[wrow] : bhf[wrow]);
}

// ---------- kernel 3: fused GEMM (bf16 MFMA) + LSTM activation + masked pool ----------
// Block tile: 128 rows (one b, t-range) x 96 packed cols (= 2 groups of 16 h-cols).
// grid = (16 n-tiles fastest for L3 reuse of A, 512 m-tiles).
// LDS XOR swizzle: chunk (row,kb) (8 bf16 = 16 B) at slot row*8 + (kb ^ (row&7)):
//   staging writes and ds_read_b128 fragment reads are both <=2-way (free, m136).
__global__ __launch_bounds__(256, 2) void gemm_pool(
    const unsigned short* __restrict__ Xb, const unsigned short* __restrict__ Wp,
    const float* __restrict__ bias_p, const int* __restrict__ lengths,
    float* __restrict__ psum, float* __restrict__ pmax)
{
    __shared__ __align__(16) short As[128 * 64];
    __shared__ __align__(16) short Bs[96 * 64];
    __shared__ float red[2][4][2][16];   // [sum/max][wave][group][col16]

    const int tid  = threadIdx.x;
    const int w    = tid >> 6;
    const int lane = tid & 63;
    const int gn   = blockIdx.x;          // 0..15
    const int m0   = blockIdx.y * 128;    // row base (within a single b)
    const int n0   = gn * 96;             // packed col base

    f32x4 acc[2][6];
    #pragma unroll
    for (int i = 0; i < 2; ++i)
        #pragma unroll
        for (int j = 0; j < 6; ++j) acc[i][j] = (f32x4){0.f, 0.f, 0.f, 0.f};

    uint4 av[4], bv[3];
    #pragma unroll
    for (int it = 0; it < 4; ++it) {
        int n = it * 256 + tid;
        av[it] = *(const uint4*)(Xb + ((m0 + (n >> 3)) * 256 + (n & 7) * 8));
    }
    #pragma unroll
    for (int it = 0; it < 3; ++it) {
        int n = it * 256 + tid;
        bv[it] = *(const uint4*)(Wp + ((n0 + (n >> 3)) * 256 + (n & 7) * 8));
    }

    #pragma unroll
    for (int kit = 0; kit < 4; ++kit) {
        #pragma unroll
        for (int it = 0; it < 4; ++it) {
            int n = it * 256 + tid;
            int slot = (n >> 3) * 8 + ((n & 7) ^ ((n >> 3) & 7));
            *(uint4*)(As + slot * 8) = av[it];
        }
        #pragma unroll
        for (int it = 0; it < 3; ++it) {
            int n = it * 256 + tid;
            int slot = (n >> 3) * 8 + ((n & 7) ^ ((n >> 3) & 7));
            *(uint4*)(Bs + slot * 8) = bv[it];
        }
        __syncthreads();
        if (kit < 3) {   // prefetch next tile while computing this one
            int k0 = (kit + 1) * 64;
            #pragma unroll
            for (int it = 0; it < 4; ++it) {
                int n = it * 256 + tid;
                av[it] = *(const uint4*)(Xb + ((m0 + (n >> 3)) * 256 + k0 + (n & 7) * 8));
            }
            #pragma unroll
            for (int it = 0; it < 3; ++it) {
                int n = it * 256 + tid;
                bv[it] = *(const uint4*)(Wp + ((n0 + (n >> 3)) * 256 + k0 + (n & 7) * 8));
            }
        }
        #pragma unroll
        for (int ks = 0; ks < 2; ++ks) {
            bf16x8 af[2], bfr[6];
            int kb = ks * 4 + (lane >> 4);
            #pragma unroll
            for (int rt = 0; rt < 2; ++rt) {
                int row = w * 32 + rt * 16 + (lane & 15);
                af[rt] = *(const bf16x8*)(As + (row * 8 + (kb ^ (row & 7))) * 8);
            }
            #pragma unroll
            for (int ct = 0; ct < 6; ++ct) {
                int row = ct * 16 + (lane & 15);
                bfr[ct] = *(const bf16x8*)(Bs + (row * 8 + (kb ^ (row & 7))) * 8);
            }
            #pragma unroll
            for (int rt = 0; rt < 2; ++rt)
                #pragma unroll
                for (int ct = 0; ct < 6; ++ct)
                    acc[rt][ct] = __builtin_amdgcn_mfma_f32_16x16x32_bf16(
                        af[rt], bfr[ct], acc[rt][ct], 0, 0, 0);
        }
        if (kit < 3) __syncthreads();
    }

    // ---- epilogue: bias + LSTM pointwise + masked sum/max pool over this tile's rows ----
    const int b  = m0 >> 11;        // T = 2048
    const int t0 = m0 & 2047;
    int lenb = lengths[b]; lenb = lenb < 1 ? 1 : (lenb > T_ ? T_ : lenb);
    const int q = lane >> 4, cc = lane & 15;

    #pragma unroll
    for (int gg = 0; gg < 2; ++gg) {
        float bi = bias_p[n0 + gg * 48 + 0  + cc];
        float bg = bias_p[n0 + gg * 48 + 16 + cc];
        float bo = bias_p[n0 + gg * 48 + 32 + cc];
        float hsum = 0.f, hmax = -1e30f;
        #pragma unroll
        for (int rt = 0; rt < 2; ++rt) {
            #pragma unroll
            for (int reg = 0; reg < 4; ++reg) {
                int row = w * 32 + rt * 16 + q * 4 + reg;   // C/D layout: row = quad*4+reg
                int t = t0 + row;
                float iv = acc[rt][gg * 3 + 0][reg] + bi;
                float gv = acc[rt][gg * 3 + 1][reg] + bg;
                float ov = acc[rt][gg * 3 + 2][reg] + bo;
                float cv = sigm_(iv) * tanh_(gv);
                float h  = sigm_(ov) * tanh_(cv);
                if (t < lenb) { hsum += h; hmax = fmaxf(hmax, h); }
            }
        }
        hsum += __shfl_xor(hsum, 16, 64);
        hmax = fmaxf(hmax, __shfl_xor(hmax, 16, 64));
        hsum += __shfl_xor(hsum, 32, 64);
        hmax = fmaxf(hmax, __shfl_xor(hmax, 32, 64));
        if (q == 0) { red[0][w][gg][cc] = hsum; red[1][w][gg][cc] = hmax; }
    }
    __syncthreads();
    if (tid < 32) {
        int gg = tid >> 4, c16 = tid & 15;
        float s  = red[0][0][gg][c16] + red[0][1][gg][c16] + red[0][2][gg][c16] + red[0][3][gg][c16];
        float mx = fmaxf(fmaxf(red[1][0][gg][c16], red[1][1][gg][c16]),
                         fmaxf(red[1][2][gg][c16], red[1][3][gg][c16]));
        int gidx = gn * 2 + gg;
        int col2 = (gidx >> 4) * 256 + (gidx & 15) * 16 + c16;   // dir*256 + c
        int mt = (m0 >> 7) & 15;
        psum[(b * 16 + mt) * 512 + col2] = s;
        pmax[(b * 16 + mt) * 512 + col2] = mx;
    }
}

// ---------- kernel 4: finish pooling + ReLU + 2-layer MLP ----------
__global__ __launch_bounds__(256) void final_mlp(
    const float* __restrict__ psum, const float* __restrict__ pmax,
    const int* __restrict__ lengths,
    const float* __restrict__ W1, const float* __restrict__ b1,
    const float* __restrict__ W2, const float* __restrict__ b2,
    float* __restrict__ out)
{
    __shared__ float doc[1024];
    __shared__ float d1[256];
    int b = blockIdx.x, tid = threadIdx.x;
    int lenb = lengths[b]; lenb = lenb < 1 ? 1 : (lenb > T_ ? T_ : lenb);
    float invlen = 1.f / (float)lenb;
    for (int col = tid; col < 512; col += 256) {
        float s = 0.f, mx = -1e30f;
        #pragma unroll
        for (int mt = 0; mt < 16; ++mt) {
            s += psum[(b * 16 + mt) * 512 + col];
            mx = fmaxf(mx, pmax[(b * 16 + mt) * 512 + col]);
        }
        doc[col]       = fmaxf(s * invlen, 0.f);   // relu(avg_pool)
        doc[512 + col] = fmaxf(mx, 0.f);           // relu(max_pool)
    }
    __syncthreads();
    {
        const float4* wrow = (const float4*)(W1 + tid * 1024);
        const float4* dv   = (const float4*)doc;
        float a0 = 0.f, a1 = 0.f, a2 = 0.f, a3 = 0.f;
        #pragma unroll 4
        for (int k = 0; k < 256; ++k) {
            float4 wv = wrow[k]; float4 xv = dv[k];
            a0 += wv.x * xv.x; a1 += wv.y * xv.y; a2 += wv.z * xv.z; a3 += wv.w * xv.w;
        }
        d1[tid] = a0 + a1 + a2 + a3 + b1[tid];
    }
    __syncthreads();
    if (tid < LBL_) {
        float a = b2[tid];
        const float* wr = W2 + tid * 256;
        #pragma unroll 8
        for (int k = 0; k < 256; ++k) a += wr[k] * d1[k];
        out[b * LBL_ + tid] = a;
    }
}

// ---------- workspace layout (bytes) ----------
#define XB_OFF   0u
#define WP_OFF   33554432u          // 65536*256*2
#define BIAS_OFF 34340864u          // + 1536*256*2
#define PSUM_OFF 34347008u          // + 1536*4
#define PMAX_OFF 35395584u          // + 32*16*512*4

extern "C" void kernel_launch(void* const* d_in, const int* in_sizes, int n_in,
                              void* d_out, int out_size, void* d_ws, size_t ws_size,
                              hipStream_t stream) {
    (void)in_sizes; (void)n_in; (void)out_size; (void)ws_size;
    const float* X      = (const float*)d_in[0];
    const int*   lens   = (const int*)d_in[1];
    const float* W_ih_f = (const float*)d_in[2];
    const float* b_ih_f = (const float*)d_in[3];
    const float* b_hh_f = (const float*)d_in[4];
    const float* W_ih_r = (const float*)d_in[5];
    const float* b_ih_r = (const float*)d_in[6];
    const float* b_hh_r = (const float*)d_in[7];
    const float* W1     = (const float*)d_in[8];
    const float* b1     = (const float*)d_in[9];
    const float* W2     = (const float*)d_in[10];
    const float* b2     = (const float*)d_in[11];
    float* out = (float*)d_out;

    char* ws = (char*)d_ws;
    unsigned short* Xb     = (unsigned short*)(ws + XB_OFF);
    unsigned short* Wp     = (unsigned short*)(ws + WP_OFF);
    float*          bias_p = (float*)(ws + BIAS_OFF);
    float*          psum   = (float*)(ws + PSUM_OFF);
    float*          pmax   = (float*)(ws + PMAX_OFF);

    cast_x<<<M_ * E_ / (256 * 8), 256, 0, stream>>>((const float4*)X, (uint4*)Xb);
    pack_w<<<NPACK_, 256, 0, stream>>>(W_ih_f, b_ih_f, b_hh_f, W_ih_r, b_ih_r, b_hh_r,
                                       Wp, bias_p);
    gemm_pool<<<dim3(16, M_ / 128), 256, 0, stream>>>(Xb, Wp, bias_p, lens, psum, pmax);
    final_mlp<<<B_, 256, 0, stream>>>(psum, pmax, lens, W1, b1, W2, b2, out);
}

// Round 2
// 234.856 us; speedup vs baseline: 1.6416x; 1.6416x over previous
//
#include <hip/hip_runtime.h>
#include <stdint.h>

// Problem constants
#define B_   32
#define T_   2048
#define E_   256
#define H_   256
#define LBL_ 20
#define M_   (B_ * T_)      // 65536 rows
#define NPACK_ 1536         // 2 dirs * 3 gates (i,g,o) * 256

typedef __attribute__((ext_vector_type(8))) short bf16x8;
typedef __attribute__((ext_vector_type(4))) float f32x4;

__device__ __forceinline__ unsigned short f2bf(float f) {
    union { float f; unsigned int u; } a; a.f = f;
    unsigned int u = a.u;
    u += 0x7FFFu + ((u >> 16) & 1u);   // RNE
    return (unsigned short)(u >> 16);
}

__device__ __forceinline__ float rcp_(float x) {
#if __has_builtin(__builtin_amdgcn_rcpf)
    return __builtin_amdgcn_rcpf(x);
#else
    return 1.0f / x;
#endif
}
__device__ __forceinline__ float sigm_(float x) {
    x = fminf(fmaxf(x, -30.f), 30.f);
    return rcp_(1.f + __expf(-x));
}
__device__ __forceinline__ float tanh_(float x) {
    x = fminf(fmaxf(x, -15.f), 15.f);
    float e = __expf(-2.f * x);
    return (1.f - e) * rcp_(1.f + e);
}

// ---------- kernel 1: cast X fp32 -> bf16 (8 elems / thread) ----------
__global__ __launch_bounds__(256) void cast_x(const float4* __restrict__ X4,
                                              uint4* __restrict__ Xb4) {
    int idx = blockIdx.x * 256 + threadIdx.x;
    float4 v0 = X4[2 * idx], v1 = X4[2 * idx + 1];
    union { unsigned short us[8]; uint4 u; } r;
    r.us[0] = f2bf(v0.x); r.us[1] = f2bf(v0.y); r.us[2] = f2bf(v0.z); r.us[3] = f2bf(v0.w);
    r.us[4] = f2bf(v1.x); r.us[5] = f2bf(v1.y); r.us[6] = f2bf(v1.z); r.us[7] = f2bf(v1.w);
    Xb4[idx] = r.u;
}

// ---------- kernel 2: pack weights ----------
// Wp row n: gidx = n/48 (dir = gidx>>4, c16 = gidx&15), r = n%48, ty = r/16 in {i,g,o},
// cc = r%16 -> source gate row = {0,2,3}[ty]*256 + c16*16 + cc.  (f gate dead: c0 == 0)
__global__ __launch_bounds__(256) void pack_w(
    const float* __restrict__ Wf, const float* __restrict__ bif, const float* __restrict__ bhf,
    const float* __restrict__ Wr, const float* __restrict__ bir, const float* __restrict__ bhr,
    unsigned short* __restrict__ Wp, float* __restrict__ bias_p)
{
    int n = blockIdx.x, t = threadIdx.x;
    int gidx = n / 48, r = n % 48;
    int ty = r >> 4, cc = r & 15;
    int dir = gidx >> 4, c = (gidx & 15) * 16 + cc;
    int gate = (ty == 0) ? 0 : (ty == 1 ? 2 : 3);
    int wrow = gate * 256 + c;
    const float* W = dir ? Wr : Wf;
    Wp[n * 256 + t] = f2bf(W[wrow * 256 + t]);
    if (t == 0)
        bias_p[n] = (dir ? bir[wrow] : bif[wrow]) + (dir ? bhr[wrow] : bhf[wrow]);
}

// ---------- kernel 3: fused GEMM (bf16 MFMA) + LSTM activation + masked pool ----------
// Block tile: 128 rows (one b, t-range) x 96 packed cols.
// Staging: __builtin_amdgcn_global_load_lds width=16 — no data-holding VGPRs (the
// round-1 kernel spilled its register prefetch buffers -> 750 MB scratch writes).
// LDS dest is wave-uniform base + lane*16, so the XOR swizzle is applied on the
// GATHER side: LDS slot s holds global chunk (row=s>>3, kb=(s&7)^(row&7)); a wave's
// 64 lanes still cover whole 128 B global rows (coalesced), and fragment
// ds_read_b128s use the same swizzle formula (<=2-way conflicts, free per m136).
// Grid: flat 8192, m_tile=(g>>7)*8+(g&7), n_tile=(g>>3)&15 — the 16 n-tiles of an
// m-tile land on one XCD (g%8 fixed) so each A row is fetched into one L2 only.
__global__ __launch_bounds__(256, 2) void gemm_pool(
    const unsigned short* __restrict__ Xb, const unsigned short* __restrict__ Wp,
    const float* __restrict__ bias_p, const int* __restrict__ lengths,
    float* __restrict__ psum, float* __restrict__ pmax)
{
    // slots: A = 0..1023 (128 rows x 8 kb), B = 1024..1791 (96 rows x 8 kb); 16 B each
    __shared__ __align__(16) short tiles[1792 * 8];
    __shared__ float red[2][4][2][16];   // [sum/max][wave][group][col16]

    short* As = tiles;
    short* Bs = tiles + 1024 * 8;

    const int tid  = threadIdx.x;
    const int w    = tid >> 6;
    const int lane = tid & 63;
    const int g    = blockIdx.x;
    const int m_tile = ((g >> 7) << 3) + (g & 7);   // 0..511
    const int n_tile = (g >> 3) & 15;               // 0..15
    const int m0   = m_tile << 7;
    const int n0   = n_tile * 96;

    // per-round staging pointers (7 rounds of 256 slots / block)
    const unsigned short* gp[7];
    short* lb[7];
    #pragma unroll
    for (int r = 0; r < 7; ++r) {
        int base_slot = r * 256 + w * 64;
        int s = base_slot + lane;
        int isA = (s < 1024);
        int sl = isA ? s : (s - 1024);
        int row = sl >> 3;
        int kb = (s & 7) ^ (row & 7);
        gp[r] = isA ? (Xb + (m0 + row) * 256 + kb * 8)
                    : (Wp + (n0 + row) * 256 + kb * 8);
        lb[r] = tiles + base_slot * 8;   // wave-uniform
    }

    f32x4 acc[2][6];
    #pragma unroll
    for (int i = 0; i < 2; ++i)
        #pragma unroll
        for (int j = 0; j < 6; ++j) acc[i][j] = (f32x4){0.f, 0.f, 0.f, 0.f};

    #pragma unroll
    for (int kit = 0; kit < 4; ++kit) {
        #pragma unroll
        for (int r = 0; r < 7; ++r)
            __builtin_amdgcn_global_load_lds(
                (const __attribute__((address_space(1))) void*)(gp[r] + kit * 64),
                (__attribute__((address_space(3))) void*)lb[r],
                16, 0, 0);
        __syncthreads();   // compiler emits s_waitcnt vmcnt(0) before s_barrier

        #pragma unroll
        for (int ks = 0; ks < 2; ++ks) {
            bf16x8 af[2], bfr[6];
            int kb = ks * 4 + (lane >> 4);
            #pragma unroll
            for (int rt = 0; rt < 2; ++rt) {
                int row = w * 32 + rt * 16 + (lane & 15);
                af[rt] = *(const bf16x8*)(As + (row * 8 + (kb ^ (row & 7))) * 8);
            }
            #pragma unroll
            for (int ct = 0; ct < 6; ++ct) {
                int row = ct * 16 + (lane & 15);
                bfr[ct] = *(const bf16x8*)(Bs + (row * 8 + (kb ^ (row & 7))) * 8);
            }
            #pragma unroll
            for (int rt = 0; rt < 2; ++rt)
                #pragma unroll
                for (int ct = 0; ct < 6; ++ct)
                    acc[rt][ct] = __builtin_amdgcn_mfma_f32_16x16x32_bf16(
                        af[rt], bfr[ct], acc[rt][ct], 0, 0, 0);
        }
        if (kit < 3) __syncthreads();   // previous tile fully consumed before overwrite
    }

    // ---- epilogue: bias + LSTM pointwise + masked sum/max pool over this tile's rows ----
    const int b  = m0 >> 11;        // T = 2048
    const int t0 = m0 & 2047;
    int lenb = lengths[b]; lenb = lenb < 1 ? 1 : (lenb > T_ ? T_ : lenb);
    const int q = lane >> 4, cc = lane & 15;

    #pragma unroll
    for (int gg = 0; gg < 2; ++gg) {
        float bi = bias_p[n0 + gg * 48 + 0  + cc];
        float bg = bias_p[n0 + gg * 48 + 16 + cc];
        float bo = bias_p[n0 + gg * 48 + 32 + cc];
        float hsum = 0.f, hmax = -1e30f;
        #pragma unroll
        for (int rt = 0; rt < 2; ++rt) {
            #pragma unroll
            for (int reg = 0; reg < 4; ++reg) {
                int row = w * 32 + rt * 16 + q * 4 + reg;   // C/D layout: row = quad*4+reg
                int t = t0 + row;
                float iv = acc[rt][gg * 3 + 0][reg] + bi;
                float gv = acc[rt][gg * 3 + 1][reg] + bg;
                float ov = acc[rt][gg * 3 + 2][reg] + bo;
                float cv = sigm_(iv) * tanh_(gv);
                float h  = sigm_(ov) * tanh_(cv);
                if (t < lenb) { hsum += h; hmax = fmaxf(hmax, h); }
            }
        }
        hsum += __shfl_xor(hsum, 16, 64);
        hmax = fmaxf(hmax, __shfl_xor(hmax, 16, 64));
        hsum += __shfl_xor(hsum, 32, 64);
        hmax = fmaxf(hmax, __shfl_xor(hmax, 32, 64));
        if (q == 0) { red[0][w][gg][cc] = hsum; red[1][w][gg][cc] = hmax; }
    }
    __syncthreads();
    if (tid < 32) {
        int gg = tid >> 4, c16 = tid & 15;
        float s  = red[0][0][gg][c16] + red[0][1][gg][c16] + red[0][2][gg][c16] + red[0][3][gg][c16];
        float mx = fmaxf(fmaxf(red[1][0][gg][c16], red[1][1][gg][c16]),
                         fmaxf(red[1][2][gg][c16], red[1][3][gg][c16]));
        int gidx = n_tile * 2 + gg;
        int col2 = (gidx >> 4) * 256 + (gidx & 15) * 16 + c16;   // dir*256 + c
        int mt = m_tile & 15;
        psum[(b * 16 + mt) * 512 + col2] = s;
        pmax[(b * 16 + mt) * 512 + col2] = mx;
    }
}

// ---------- kernel 4: finish pooling + ReLU + 2-layer MLP ----------
__global__ __launch_bounds__(256) void final_mlp(
    const float* __restrict__ psum, const float* __restrict__ pmax,
    const int* __restrict__ lengths,
    const float* __restrict__ W1, const float* __restrict__ b1,
    const float* __restrict__ W2, const float* __restrict__ b2,
    float* __restrict__ out)
{
    __shared__ float doc[1024];
    __shared__ float d1[256];
    int b = blockIdx.x, tid = threadIdx.x;
    int lenb = lengths[b]; lenb = lenb < 1 ? 1 : (lenb > T_ ? T_ : lenb);
    float invlen = 1.f / (float)lenb;
    for (int col = tid; col < 512; col += 256) {
        float s = 0.f, mx = -1e30f;
        #pragma unroll
        for (int mt = 0; mt < 16; ++mt) {
            s += psum[(b * 16 + mt) * 512 + col];
            mx = fmaxf(mx, pmax[(b * 16 + mt) * 512 + col]);
        }
        doc[col]       = fmaxf(s * invlen, 0.f);   // relu(avg_pool)
        doc[512 + col] = fmaxf(mx, 0.f);           // relu(max_pool)
    }
    __syncthreads();
    {
        const float4* wrow = (const float4*)(W1 + tid * 1024);
        const float4* dv   = (const float4*)doc;
        float a0 = 0.f, a1 = 0.f, a2 = 0.f, a3 = 0.f;
        #pragma unroll 4
        for (int k = 0; k < 256; ++k) {
            float4 wv = wrow[k]; float4 xv = dv[k];
            a0 += wv.x * xv.x; a1 += wv.y * xv.y; a2 += wv.z * xv.z; a3 += wv.w * xv.w;
        }
        d1[tid] = a0 + a1 + a2 + a3 + b1[tid];
    }
    __syncthreads();
    if (tid < LBL_) {
        float a = b2[tid];
        const float* wr = W2 + tid * 256;
        #pragma unroll 8
        for (int k = 0; k < 256; ++k) a += wr[k] * d1[k];
        out[b * LBL_ + tid] = a;
    }
}

// ---------- workspace layout (bytes) ----------
#define XB_OFF   0u
#define WP_OFF   33554432u          // 65536*256*2
#define BIAS_OFF 34340864u          // + 1536*256*2
#define PSUM_OFF 34347008u          // + 1536*4
#define PMAX_OFF 35395584u          // + 32*16*512*4

extern "C" void kernel_launch(void* const* d_in, const int* in_sizes, int n_in,
                              void* d_out, int out_size, void* d_ws, size_t ws_size,
                              hipStream_t stream) {
    (void)in_sizes; (void)n_in; (void)out_size; (void)ws_size;
    const float* X      = (const float*)d_in[0];
    const int*   lens   = (const int*)d_in[1];
    const float* W_ih_f = (const float*)d_in[2];
    const float* b_ih_f = (const float*)d_in[3];
    const float* b_hh_f = (const float*)d_in[4];
    const float* W_ih_r = (const float*)d_in[5];
    const float* b_ih_r = (const float*)d_in[6];
    const float* b_hh_r = (const float*)d_in[7];
    const float* W1     = (const float*)d_in[8];
    const float* b1     = (const float*)d_in[9];
    const float* W2     = (const float*)d_in[10];
    const float* b2     = (const float*)d_in[11];
    float* out = (float*)d_out;

    char* ws = (char*)d_ws;
    unsigned short* Xb     = (unsigned short*)(ws + XB_OFF);
    unsigned short* Wp     = (unsigned short*)(ws + WP_OFF);
    float*          bias_p = (float*)(ws + BIAS_OFF);
    float*          psum   = (float*)(ws + PSUM_OFF);
    float*          pmax   = (float*)(ws + PMAX_OFF);

    cast_x<<<M_ * E_ / (256 * 8), 256, 0, stream>>>((const float4*)X, (uint4*)Xb);
    pack_w<<<NPACK_, 256, 0, stream>>>(W_ih_f, b_ih_f, b_hh_f, W_ih_r, b_ih_r, b_hh_r,
                                       Wp, bias_p);
    gemm_pool<<<dim3(8192), 256, 0, stream>>>(Xb, Wp, bias_p, lens, psum, pmax);
    final_mlp<<<B_, 256, 0, stream>>>(psum, pmax, lens, W1, b1, W2, b2, out);
}

// Round 4
// 201.060 us; speedup vs baseline: 1.9176x; 1.1681x over previous
//
#include <hip/hip_runtime.h>
#include <stdint.h>

// Problem constants
#define B_   32
#define T_   2048
#define E_   256
#define H_   256
#define LBL_ 20
#define M_   (B_ * T_)      // 65536 rows
#define NPACK_ 1536         // 2 dirs * 3 gates (i,g,o) * 256

typedef __attribute__((ext_vector_type(8))) short bf16x8;
typedef __attribute__((ext_vector_type(4))) float f32x4;

__device__ __forceinline__ unsigned short f2bf(float f) {
    union { float f; unsigned int u; } a; a.f = f;
    unsigned int u = a.u;
    u += 0x7FFFu + ((u >> 16) & 1u);   // RNE
    return (unsigned short)(u >> 16);
}

__device__ __forceinline__ float rcp_(float x) {
#if __has_builtin(__builtin_amdgcn_rcpf)
    return __builtin_amdgcn_rcpf(x);
#else
    return 1.0f / x;
#endif
}
// 2^x via v_exp_f32 (__exp2f is CUDA-only; HIP needs the amdgcn builtin)
__device__ __forceinline__ float exp2_(float x) {
#if __has_builtin(__builtin_amdgcn_exp2f)
    return __builtin_amdgcn_exp2f(x);
#else
    return exp2f(x);
#endif
}
// sigmoid via exp2: x->+inf: exp2->0 -> 1; x->-inf: exp2->inf -> rcp(inf)=0. No clamps needed.
__device__ __forceinline__ float sigm_(float x) {
    return rcp_(1.f + exp2_(x * -1.44269504f));
}
// tanh(x) = 1 - 2/(1+e^{2x}); x->+inf: 1-0=1; x->-inf: 1-2= -1. NaN-free at both ends.
__device__ __forceinline__ float tanhs_(float x) {
    return __builtin_fmaf(-2.f, rcp_(1.f + exp2_(x * 2.88539008f)), 1.f);
}
// tanh for |c| <= 1 (c = sigma*tanh product): Pade(5,4), err < ~1e-6 on [-1,1], no exp.
__device__ __forceinline__ float tanhp_(float c) {
    float t = c * c;
    float num = c * __builtin_fmaf(t, t + 105.f, 945.f);
    float den = __builtin_fmaf(t, __builtin_fmaf(t, 15.f, 420.f), 945.f);
    return num * rcp_(den);
}

// ---------- kernel 1: cast X fp32 -> bf16 (8 elems / thread), skipping dead rows ----------
// grid = (256 t-tiles of 8 rows, 32 b). Rows >= ceil(len/128)*128 are never read by
// gemm_pool (whole m-tile skipped there), so don't cast them.
__global__ __launch_bounds__(256) void cast_x(const float4* __restrict__ X4,
                                              uint4* __restrict__ Xb4,
                                              const int* __restrict__ lengths) {
    int b = blockIdx.y, tile = blockIdx.x;
    int lenb = lengths[b]; lenb = lenb < 1 ? 1 : (lenb > T_ ? T_ : lenb);
    int used = (lenb + 127) & ~127;
    if (tile * 8 >= used) return;
    int idx = b * 65536 + tile * 256 + threadIdx.x;   // units of 8 floats
    float4 v0 = X4[2 * idx], v1 = X4[2 * idx + 1];
    union { unsigned short us[8]; uint4 u; } r;
    r.us[0] = f2bf(v0.x); r.us[1] = f2bf(v0.y); r.us[2] = f2bf(v0.z); r.us[3] = f2bf(v0.w);
    r.us[4] = f2bf(v1.x); r.us[5] = f2bf(v1.y); r.us[6] = f2bf(v1.z); r.us[7] = f2bf(v1.w);
    Xb4[idx] = r.u;
}

// ---------- kernel 2: pack weights ----------
// Wp row n: gidx = n/48 (dir = gidx>>4, c16 = gidx&15), r = n%48, ty = r/16 in {i,g,o},
// cc = r%16 -> source gate row = {0,2,3}[ty]*256 + c16*16 + cc.  (f gate dead: c0 == 0)
__global__ __launch_bounds__(256) void pack_w(
    const float* __restrict__ Wf, const float* __restrict__ bif, const float* __restrict__ bhf,
    const float* __restrict__ Wr, const float* __restrict__ bir, const float* __restrict__ bhr,
    unsigned short* __restrict__ Wp, float* __restrict__ bias_p)
{
    int n = blockIdx.x, t = threadIdx.x;
    int gidx = n / 48, r = n % 48;
    int ty = r >> 4, cc = r & 15;
    int dir = gidx >> 4, c = (gidx & 15) * 16 + cc;
    int gate = (ty == 0) ? 0 : (ty == 1 ? 2 : 3);
    int wrow = gate * 256 + c;
    const float* W = dir ? Wr : Wf;
    Wp[n * 256 + t] = f2bf(W[wrow * 256 + t]);
    if (t == 0)
        bias_p[n] = (dir ? bir[wrow] : bif[wrow]) + (dir ? bhr[wrow] : bhf[wrow]);
}

// ---------- kernel 3: fused GEMM (bf16 MFMA) + LSTM activation + masked pool ----------
// Block tile: 128 rows (one b, t-range) x 96 packed cols. global_load_lds staging
// (width=16), gather-side XOR swizzle, flat grid with XCD-friendly mapping.
// Block-level skip of fully-masked m-tiles (t0 >= len[b]) — expected ~47% of
// blocks with uniform lengths — and wave-uniform 16-row-group skip in the epilogue.
__global__ __launch_bounds__(256, 2) void gemm_pool(
    const unsigned short* __restrict__ Xb, const unsigned short* __restrict__ Wp,
    const float* __restrict__ bias_p, const int* __restrict__ lengths,
    float* __restrict__ psum, float* __restrict__ pmax)
{
    // slots: A = 0..1023 (128 rows x 8 kb), B = 1024..1791 (96 rows x 8 kb); 16 B each
    __shared__ __align__(16) short tiles[1792 * 8];
    __shared__ float red[2][4][2][16];   // [sum/max][wave][group][col16]

    short* As = tiles;
    short* Bs = tiles + 1024 * 8;

    const int tid  = threadIdx.x;
    const int w    = tid >> 6;
    const int lane = tid & 63;
    const int g    = blockIdx.x;
    const int m_tile = ((g >> 7) << 3) + (g & 7);   // 0..511
    const int n_tile = (g >> 3) & 15;               // 0..15
    const int m0   = m_tile << 7;
    const int n0   = n_tile * 96;

    const int b  = m0 >> 11;        // T = 2048
    const int t0 = m0 & 2047;
    int lenb = lengths[b]; lenb = lenb < 1 ? 1 : (lenb > T_ ? T_ : lenb);

    // fully-masked tile: contributes (sum=0, max=-inf); skip all GEMM + epilogue work
    if (t0 >= lenb) {
        if (tid < 32) {
            int gg = tid >> 4, c16 = tid & 15;
            int gidx = n_tile * 2 + gg;
            int col2 = (gidx >> 4) * 256 + (gidx & 15) * 16 + c16;
            int mt = m_tile & 15;
            psum[(b * 16 + mt) * 512 + col2] = 0.f;
            pmax[(b * 16 + mt) * 512 + col2] = -1e30f;
        }
        return;
    }

    // per-round staging pointers (7 rounds of 256 slots / block)
    const unsigned short* gp[7];
    short* lb[7];
    #pragma unroll
    for (int r = 0; r < 7; ++r) {
        int base_slot = r * 256 + w * 64;
        int s = base_slot + lane;
        int isA = (s < 1024);
        int sl = isA ? s : (s - 1024);
        int row = sl >> 3;
        int kb = (s & 7) ^ (row & 7);
        gp[r] = isA ? (Xb + (m0 + row) * 256 + kb * 8)
                    : (Wp + (n0 + row) * 256 + kb * 8);
        lb[r] = tiles + base_slot * 8;   // wave-uniform
    }

    f32x4 acc[2][6];
    #pragma unroll
    for (int i = 0; i < 2; ++i)
        #pragma unroll
        for (int j = 0; j < 6; ++j) acc[i][j] = (f32x4){0.f, 0.f, 0.f, 0.f};

    #pragma unroll
    for (int kit = 0; kit < 4; ++kit) {
        #pragma unroll
        for (int r = 0; r < 7; ++r)
            __builtin_amdgcn_global_load_lds(
                (const __attribute__((address_space(1))) void*)(gp[r] + kit * 64),
                (__attribute__((address_space(3))) void*)lb[r],
                16, 0, 0);
        __syncthreads();   // compiler emits s_waitcnt vmcnt(0) before s_barrier

        #pragma unroll
        for (int ks = 0; ks < 2; ++ks) {
            bf16x8 af[2], bfr[6];
            int kb = ks * 4 + (lane >> 4);
            #pragma unroll
            for (int rt = 0; rt < 2; ++rt) {
                int row = w * 32 + rt * 16 + (lane & 15);
                af[rt] = *(const bf16x8*)(As + (row * 8 + (kb ^ (row & 7))) * 8);
            }
            #pragma unroll
            for (int ct = 0; ct < 6; ++ct) {
                int row = ct * 16 + (lane & 15);
                bfr[ct] = *(const bf16x8*)(Bs + (row * 8 + (kb ^ (row & 7))) * 8);
            }
            #pragma unroll
            for (int rt = 0; rt < 2; ++rt)
                #pragma unroll
                for (int ct = 0; ct < 6; ++ct)
                    acc[rt][ct] = __builtin_amdgcn_mfma_f32_16x16x32_bf16(
                        af[rt], bfr[ct], acc[rt][ct], 0, 0, 0);
        }
        if (kit < 3) __syncthreads();   // previous tile fully consumed before overwrite
    }

    // ---- epilogue: bias + LSTM pointwise + masked sum/max pool over this tile's rows ----
    const int q = lane >> 4, cc = lane & 15;

    #pragma unroll
    for (int gg = 0; gg < 2; ++gg) {
        float bi = bias_p[n0 + gg * 48 + 0  + cc];
        float bg = bias_p[n0 + gg * 48 + 16 + cc];
        float bo = bias_p[n0 + gg * 48 + 32 + cc];
        float hsum = 0.f, hmax = -1e30f;
        #pragma unroll
        for (int rt = 0; rt < 2; ++rt) {
            // wave-uniform skip: rows of this 16-row group all >= len[b]
            if (t0 + w * 32 + rt * 16 >= lenb) continue;
            #pragma unroll
            for (int reg = 0; reg < 4; ++reg) {
                int row = w * 32 + rt * 16 + q * 4 + reg;   // C/D layout: row = quad*4+reg
                int t = t0 + row;
                float iv = acc[rt][gg * 3 + 0][reg] + bi;
                float gv = acc[rt][gg * 3 + 1][reg] + bg;
                float ov = acc[rt][gg * 3 + 2][reg] + bo;
                float cv = sigm_(iv) * tanhs_(gv);
                float h  = sigm_(ov) * tanhp_(cv);   // |cv| < 1 -> Pade, no exp
                if (t < lenb) { hsum += h; hmax = fmaxf(hmax, h); }
            }
        }
        hsum += __shfl_xor(hsum, 16, 64);
        hmax = fmaxf(hmax, __shfl_xor(hmax, 16, 64));
        hsum += __shfl_xor(hsum, 32, 64);
        hmax = fmaxf(hmax, __shfl_xor(hmax, 32, 64));
        if (q == 0) { red[0][w][gg][cc] = hsum; red[1][w][gg][cc] = hmax; }
    }
    __syncthreads();
    if (tid < 32) {
        int gg = tid >> 4, c16 = tid & 15;
        float s  = red[0][0][gg][c16] + red[0][1][gg][c16] + red[0][2][gg][c16] + red[0][3][gg][c16];
        float mx = fmaxf(fmaxf(red[1][0][gg][c16], red[1][1][gg][c16]),
                         fmaxf(red[1][2][gg][c16], red[1][3][gg][c16]));
        int gidx = n_tile * 2 + gg;
        int col2 = (gidx >> 4) * 256 + (gidx & 15) * 16 + c16;   // dir*256 + c
        int mt = m_tile & 15;
        psum[(b * 16 + mt) * 512 + col2] = s;
        pmax[(b * 16 + mt) * 512 + col2] = mx;
    }
}

// ---------- kernel 4: finish pooling + ReLU + 2-layer MLP ----------
__global__ __launch_bounds__(256) void final_mlp(
    const float* __restrict__ psum, const float* __restrict__ pmax,
    const int* __restrict__ lengths,
    const float* __restrict__ W1, const float* __restrict__ b1,
    const float* __restrict__ W2, const float* __restrict__ b2,
    float* __restrict__ out)
{
    __shared__ float doc[1024];
    __shared__ float d1[256];
    int b = blockIdx.x, tid = threadIdx.x;
    int lenb = lengths[b]; lenb = lenb < 1 ? 1 : (lenb > T_ ? T_ : lenb);
    float invlen = 1.f / (float)lenb;
    for (int col = tid; col < 512; col += 256) {
        float s = 0.f, mx = -1e30f;
        #pragma unroll
        for (int mt = 0; mt < 16; ++mt) {
            s += psum[(b * 16 + mt) * 512 + col];
            mx = fmaxf(mx, pmax[(b * 16 + mt) * 512 + col]);
        }
        doc[col]       = fmaxf(s * invlen, 0.f);   // relu(avg_pool)
        doc[512 + col] = fmaxf(mx, 0.f);           // relu(max_pool)
    }
    __syncthreads();
    {
        const float4* wrow = (const float4*)(W1 + tid * 1024);
        const float4* dv   = (const float4*)doc;
        float a0 = 0.f, a1 = 0.f, a2 = 0.f, a3 = 0.f;
        #pragma unroll 4
        for (int k = 0; k < 256; ++k) {
            float4 wv = wrow[k]; float4 xv = dv[k];
            a0 += wv.x * xv.x; a1 += wv.y * xv.y; a2 += wv.z * xv.z; a3 += wv.w * xv.w;
        }
        d1[tid] = a0 + a1 + a2 + a3 + b1[tid];
    }
    __syncthreads();
    if (tid < LBL_) {
        float a = b2[tid];
        const float* wr = W2 + tid * 256;
        #pragma unroll 8
        for (int k = 0; k < 256; ++k) a += wr[k] * d1[k];
        out[b * LBL_ + tid] = a;
    }
}

// ---------- workspace layout (bytes) ----------
#define XB_OFF   0u
#define WP_OFF   33554432u          // 65536*256*2
#define BIAS_OFF 34340864u          // + 1536*256*2
#define PSUM_OFF 34347008u          // + 1536*4
#define PMAX_OFF 35395584u          // + 32*16*512*4

extern "C" void kernel_launch(void* const* d_in, const int* in_sizes, int n_in,
                              void* d_out, int out_size, void* d_ws, size_t ws_size,
                              hipStream_t stream) {
    (void)in_sizes; (void)n_in; (void)out_size; (void)ws_size;
    const float* X      = (const float*)d_in[0];
    const int*   lens   = (const int*)d_in[1];
    const float* W_ih_f = (const float*)d_in[2];
    const float* b_ih_f = (const float*)d_in[3];
    const float* b_hh_f = (const float*)d_in[4];
    const float* W_ih_r = (const float*)d_in[5];
    const float* b_ih_r = (const float*)d_in[6];
    const float* b_hh_r = (const float*)d_in[7];
    const float* W1     = (const float*)d_in[8];
    const float* b1     = (const float*)d_in[9];
    const float* W2     = (const float*)d_in[10];
    const float* b2     = (const float*)d_in[11];
    float* out = (float*)d_out;

    char* ws = (char*)d_ws;
    unsigned short* Xb     = (unsigned short*)(ws + XB_OFF);
    unsigned short* Wp     = (unsigned short*)(ws + WP_OFF);
    float*          bias_p = (float*)(ws + BIAS_OFF);
    float*          psum   = (float*)(ws + PSUM_OFF);
    float*          pmax   = (float*)(ws + PMAX_OFF);

    cast_x<<<dim3(256, 32), 256, 0, stream>>>((const float4*)X, (uint4*)Xb, lens);
    pack_w<<<NPACK_, 256, 0, stream>>>(W_ih_f, b_ih_f, b_hh_f, W_ih_r, b_ih_r, b_hh_r,
                                       Wp, bias_p);
    gemm_pool<<<dim3(8192), 256, 0, stream>>>(Xb, Wp, bias_p, lens, psum, pmax);
    final_mlp<<<B_, 256, 0, stream>>>(psum, pmax, lens, W1, b1, W2, b2, out);
}

// Round 5
// 198.610 us; speedup vs baseline: 1.9412x; 1.0123x over previous
//
#include <hip/hip_runtime.h>
#include <stdint.h>

// Problem constants
#define B_   32
#define T_   2048
#define E_   256
#define H_   256
#define LBL_ 20
#define M_   (B_ * T_)      // 65536 rows
#define NPACK_ 1536         // 2 dirs * 3 gates (i,g,o) * 256

typedef __attribute__((ext_vector_type(8))) short bf16x8;
typedef __attribute__((ext_vector_type(4))) float f32x4;

__device__ __forceinline__ unsigned short f2bf(float f) {
    union { float f; unsigned int u; } a; a.f = f;
    unsigned int u = a.u;
    u += 0x7FFFu + ((u >> 16) & 1u);   // RNE
    return (unsigned short)(u >> 16);
}

__device__ __forceinline__ float rcp_(float x) {
#if __has_builtin(__builtin_amdgcn_rcpf)
    return __builtin_amdgcn_rcpf(x);
#else
    return 1.0f / x;
#endif
}
// 2^x via v_exp_f32 (__exp2f is CUDA-only; HIP needs the amdgcn builtin)
__device__ __forceinline__ float exp2_(float x) {
#if __has_builtin(__builtin_amdgcn_exp2f)
    return __builtin_amdgcn_exp2f(x);
#else
    return exp2f(x);
#endif
}
// sigmoid via exp2: x->+inf -> 1; x->-inf: rcp(inf)=0. No clamps needed.
__device__ __forceinline__ float sigm_(float x) {
    return rcp_(1.f + exp2_(x * -1.44269504f));
}
// tanh(x) = 1 - 2/(1+e^{2x}); NaN-free at both ends.
__device__ __forceinline__ float tanhs_(float x) {
    return __builtin_fmaf(-2.f, rcp_(1.f + exp2_(x * 2.88539008f)), 1.f);
}
// tanh for |c| <= 1: Pade(5,4), err < ~1e-6 on [-1,1], no exp.
__device__ __forceinline__ float tanhp_(float c) {
    float t = c * c;
    float num = c * __builtin_fmaf(t, t + 105.f, 945.f);
    float den = __builtin_fmaf(t, __builtin_fmaf(t, 15.f, 420.f), 945.f);
    return num * rcp_(den);
}

// ---------- kernel 1: fused cast X->bf16 (live rows only) + weight pack ----------
// flat grid: blocks [0,8192) cast (b = bi>>8, tile = bi&255), [8192, 9728) pack.
__global__ __launch_bounds__(256) void prep(
    const float4* __restrict__ X4, uint4* __restrict__ Xb4,
    const int* __restrict__ lengths,
    const float* __restrict__ Wf, const float* __restrict__ bif, const float* __restrict__ bhf,
    const float* __restrict__ Wr, const float* __restrict__ bir, const float* __restrict__ bhr,
    unsigned short* __restrict__ Wp, float* __restrict__ bias_p)
{
    int bi = blockIdx.x;
    if (bi < 8192) {
        int b = bi >> 8, tile = bi & 255;
        int lenb = lengths[b]; lenb = lenb < 1 ? 1 : (lenb > T_ ? T_ : lenb);
        int used = (lenb + 127) & ~127;
        if (tile * 8 >= used) return;   // rows never touched by gemm (tile skipped)
        int idx = b * 65536 + tile * 256 + threadIdx.x;   // units of 8 floats
        float4 v0 = X4[2 * idx], v1 = X4[2 * idx + 1];
        union { unsigned short us[8]; uint4 u; } r;
        r.us[0] = f2bf(v0.x); r.us[1] = f2bf(v0.y); r.us[2] = f2bf(v0.z); r.us[3] = f2bf(v0.w);
        r.us[4] = f2bf(v1.x); r.us[5] = f2bf(v1.y); r.us[6] = f2bf(v1.z); r.us[7] = f2bf(v1.w);
        Xb4[idx] = r.u;
    } else {
        // Wp row n: gidx=n/48 (dir=gidx>>4, c16=gidx&15), r=n%48, ty=r/16 in {i,g,o}
        int n = bi - 8192, t = threadIdx.x;
        int gidx = n / 48, r = n % 48;
        int ty = r >> 4, cc = r & 15;
        int dir = gidx >> 4, c = (gidx & 15) * 16 + cc;
        int gate = (ty == 0) ? 0 : (ty == 1 ? 2 : 3);
        int wrow = gate * 256 + c;
        const float* W = dir ? Wr : Wf;
        Wp[n * 256 + t] = f2bf(W[wrow * 256 + t]);
        if (t == 0)
            bias_p[n] = (dir ? bir[wrow] : bif[wrow]) + (dir ? bhr[wrow] : bhf[wrow]);
    }
}

// ---------- kernel 2: fused GEMM (bf16 MFMA) + LSTM activation + masked pool ----------
// 128x96 tile, global_load_lds (width=16), gather-side XOR swizzle, dead-tile skip.
// NEW: double-buffered LDS K-loop — loads for kit+1 issued right after the barrier,
// BEFORE compute(kit), so the next barrier's vmcnt(0) drain lands a full compute
// phase after issue (stalls were ~75% of wall in the single-buffer version).
__global__ __launch_bounds__(256, 2) void gemm_pool(
    const unsigned short* __restrict__ Xb, const unsigned short* __restrict__ Wp,
    const float* __restrict__ bias_p, const int* __restrict__ lengths,
    float* __restrict__ psum, float* __restrict__ pmax)
{
    // per buffer: A slots 0..1023 (128 rows x 8 kb), B slots 1024..1791 (96 x 8); 16 B each
    __shared__ __align__(16) short tiles[2][1792 * 8];
    __shared__ float red[2][4][2][16];   // [sum/max][wave][group][col16]

    const int tid  = threadIdx.x;
    const int w    = tid >> 6;
    const int lane = tid & 63;
    const int g    = blockIdx.x;
    const int m_tile = ((g >> 7) << 3) + (g & 7);   // 0..511
    const int n_tile = (g >> 3) & 15;               // 0..15
    const int m0   = m_tile << 7;
    const int n0   = n_tile * 96;

    const int b  = m0 >> 11;        // T = 2048
    const int t0 = m0 & 2047;
    int lenb = lengths[b]; lenb = lenb < 1 ? 1 : (lenb > T_ ? T_ : lenb);

    // fully-masked tile: contributes (sum=0, max=-inf); skip everything
    if (t0 >= lenb) {
        if (tid < 32) {
            int gg = tid >> 4, c16 = tid & 15;
            int gidx = n_tile * 2 + gg;
            int col2 = (gidx >> 4) * 256 + (gidx & 15) * 16 + c16;
            int mt = m_tile & 15;
            psum[(b * 16 + mt) * 512 + col2] = 0.f;
            pmax[(b * 16 + mt) * 512 + col2] = -1e30f;
        }
        return;
    }

    // per-round staging pointers (7 rounds of 256 slots / block)
    const unsigned short* gp[7];
    int lbs[7];   // slot-base *8 shorts within a buffer (wave-uniform)
    #pragma unroll
    for (int r = 0; r < 7; ++r) {
        int base_slot = r * 256 + w * 64;
        int s = base_slot + lane;
        int isA = (s < 1024);
        int sl = isA ? s : (s - 1024);
        int row = sl >> 3;
        int kb = (s & 7) ^ (row & 7);
        gp[r] = isA ? (Xb + (m0 + row) * 256 + kb * 8)
                    : (Wp + (n0 + row) * 256 + kb * 8);
        lbs[r] = base_slot * 8;
    }

    f32x4 acc[2][6];
    #pragma unroll
    for (int i = 0; i < 2; ++i)
        #pragma unroll
        for (int j = 0; j < 6; ++j) acc[i][j] = (f32x4){0.f, 0.f, 0.f, 0.f};

    // prologue: kit 0 -> buf 0
    #pragma unroll
    for (int r = 0; r < 7; ++r)
        __builtin_amdgcn_global_load_lds(
            (const __attribute__((address_space(1))) void*)(gp[r]),
            (__attribute__((address_space(3))) void*)(&tiles[0][0] + lbs[r]),
            16, 0, 0);

    #pragma unroll
    for (int kit = 0; kit < 4; ++kit) {
        __syncthreads();   // drains my kit-loads (vmcnt 0); all waves done with buf[(kit+1)&1]
        if (kit < 3) {     // issue kit+1 into the other buffer BEFORE computing kit
            #pragma unroll
            for (int r = 0; r < 7; ++r)
                __builtin_amdgcn_global_load_lds(
                    (const __attribute__((address_space(1))) void*)(gp[r] + (kit + 1) * 64),
                    (__attribute__((address_space(3))) void*)(&tiles[(kit + 1) & 1][0] + lbs[r]),
                    16, 0, 0);
        }
        const short* As = &tiles[kit & 1][0];
        const short* Bs = As + 1024 * 8;

        #pragma unroll
        for (int ks = 0; ks < 2; ++ks) {
            bf16x8 af[2], bfr[6];
            int kb = ks * 4 + (lane >> 4);
            #pragma unroll
            for (int rt = 0; rt < 2; ++rt) {
                int row = w * 32 + rt * 16 + (lane & 15);
                af[rt] = *(const bf16x8*)(As + (row * 8 + (kb ^ (row & 7))) * 8);
            }
            #pragma unroll
            for (int ct = 0; ct < 6; ++ct) {
                int row = ct * 16 + (lane & 15);
                bfr[ct] = *(const bf16x8*)(Bs + (row * 8 + (kb ^ (row & 7))) * 8);
            }
            #pragma unroll
            for (int rt = 0; rt < 2; ++rt)
                #pragma unroll
                for (int ct = 0; ct < 6; ++ct)
                    acc[rt][ct] = __builtin_amdgcn_mfma_f32_16x16x32_bf16(
                        af[rt], bfr[ct], acc[rt][ct], 0, 0, 0);
        }
    }

    // ---- epilogue: bias + LSTM pointwise + masked sum/max pool ----
    const int q = lane >> 4, cc = lane & 15;

    #pragma unroll
    for (int gg = 0; gg < 2; ++gg) {
        float bi = bias_p[n0 + gg * 48 + 0  + cc];
        float bg = bias_p[n0 + gg * 48 + 16 + cc];
        float bo = bias_p[n0 + gg * 48 + 32 + cc];
        float hsum = 0.f, hmax = -1e30f;
        #pragma unroll
        for (int rt = 0; rt < 2; ++rt) {
            if (t0 + w * 32 + rt * 16 >= lenb) continue;   // wave-uniform group skip
            #pragma unroll
            for (int reg = 0; reg < 4; ++reg) {
                int row = w * 32 + rt * 16 + q * 4 + reg;   // C/D: row = quad*4+reg
                int t = t0 + row;
                float iv = acc[rt][gg * 3 + 0][reg] + bi;
                float gv = acc[rt][gg * 3 + 1][reg] + bg;
                float ov = acc[rt][gg * 3 + 2][reg] + bo;
                float cv = sigm_(iv) * tanhs_(gv);
                float h  = sigm_(ov) * tanhp_(cv);   // |cv| < 1 -> Pade, no exp
                if (t < lenb) { hsum += h; hmax = fmaxf(hmax, h); }
            }
        }
        hsum += __shfl_xor(hsum, 16, 64);
        hmax = fmaxf(hmax, __shfl_xor(hmax, 16, 64));
        hsum += __shfl_xor(hsum, 32, 64);
        hmax = fmaxf(hmax, __shfl_xor(hmax, 32, 64));
        if (q == 0) { red[0][w][gg][cc] = hsum; red[1][w][gg][cc] = hmax; }
    }
    __syncthreads();
    if (tid < 32) {
        int gg = tid >> 4, c16 = tid & 15;
        float s  = red[0][0][gg][c16] + red[0][1][gg][c16] + red[0][2][gg][c16] + red[0][3][gg][c16];
        float mx = fmaxf(fmaxf(red[1][0][gg][c16], red[1][1][gg][c16]),
                         fmaxf(red[1][2][gg][c16], red[1][3][gg][c16]));
        int gidx = n_tile * 2 + gg;
        int col2 = (gidx >> 4) * 256 + (gidx & 15) * 16 + c16;   // dir*256 + c
        int mt = m_tile & 15;
        psum[(b * 16 + mt) * 512 + col2] = s;
        pmax[(b * 16 + mt) * 512 + col2] = mx;
    }
}

// ---------- kernel 3: finish pooling + ReLU + d1 = rel@W1^T + b1 ----------
// grid (4 neuron-tiles, 32 b): 4x the CU coverage of the old 32-block version;
// each block redundantly re-reduces doc (64 KB of partials — cheap, L2-resident).
__global__ __launch_bounds__(256) void mlp1(
    const float* __restrict__ psum, const float* __restrict__ pmax,
    const int* __restrict__ lengths,
    const float* __restrict__ W1, const float* __restrict__ b1,
    float* __restrict__ d1g)
{
    __shared__ float doc[1024];
    int nt = blockIdx.x, b = blockIdx.y, tid = threadIdx.x;
    int lenb = lengths[b]; lenb = lenb < 1 ? 1 : (lenb > T_ ? T_ : lenb);
    float invlen = 1.f / (float)lenb;
    for (int col = tid; col < 512; col += 256) {
        float s = 0.f, mx = -1e30f;
        #pragma unroll
        for (int mt = 0; mt < 16; ++mt) {
            s += psum[(b * 16 + mt) * 512 + col];
            mx = fmaxf(mx, pmax[(b * 16 + mt) * 512 + col]);
        }
        doc[col]       = fmaxf(s * invlen, 0.f);   // relu(avg_pool)
        doc[512 + col] = fmaxf(mx, 0.f);           // relu(max_pool)
    }
    __syncthreads();
    int neuron = tid >> 2, tq = tid & 3;           // 64 neurons x 4 threads
    int row = nt * 64 + neuron;
    const float4* wrow = (const float4*)(W1 + row * 1024 + tq * 256);
    const float4* dv   = (const float4*)doc + tq * 64;
    float a0 = 0.f, a1 = 0.f, a2 = 0.f, a3 = 0.f;
    #pragma unroll 4
    for (int k = 0; k < 64; ++k) {
        float4 wv = wrow[k]; float4 xv = dv[k];
        a0 += wv.x * xv.x; a1 += wv.y * xv.y; a2 += wv.z * xv.z; a3 += wv.w * xv.w;
    }
    float a = a0 + a1 + a2 + a3;
    a += __shfl_xor(a, 1, 64);
    a += __shfl_xor(a, 2, 64);
    if (tq == 0) d1g[b * 256 + row] = a + b1[row];
}

// ---------- kernel 4: out = d1@W2^T + b2 ----------
__global__ __launch_bounds__(256) void mlp2(
    const float* __restrict__ d1g,
    const float* __restrict__ W2, const float* __restrict__ b2,
    float* __restrict__ out)
{
    __shared__ float d1s[256];
    int b = blockIdx.x, tid = threadIdx.x;
    d1s[tid] = d1g[b * 256 + tid];
    __syncthreads();
    int j = tid >> 3, tq = tid & 7;   // 32 j-slots (20 active) x 8 threads
    float a = 0.f;
    if (j < LBL_) {
        const float4* wr = (const float4*)(W2 + j * 256) + tq * 8;
        const float4* dd = (const float4*)d1s + tq * 8;
        #pragma unroll
        for (int k = 0; k < 8; ++k) {
            float4 wv = wr[k]; float4 xv = dd[k];
            a += wv.x * xv.x + wv.y * xv.y + wv.z * xv.z + wv.w * xv.w;
        }
    }
    a += __shfl_xor(a, 1, 64);
    a += __shfl_xor(a, 2, 64);
    a += __shfl_xor(a, 4, 64);
    if (j < LBL_ && tq == 0) out[b * LBL_ + j] = a + b2[j];
}

// ---------- workspace layout (bytes) ----------
#define XB_OFF   0u
#define WP_OFF   33554432u          // 65536*256*2
#define BIAS_OFF 34340864u          // + 1536*256*2
#define PSUM_OFF 34347008u          // + 1536*4
#define PMAX_OFF 35395584u          // + 32*16*512*4
#define D1_OFF   36444160u          // + 32*16*512*4

extern "C" void kernel_launch(void* const* d_in, const int* in_sizes, int n_in,
                              void* d_out, int out_size, void* d_ws, size_t ws_size,
                              hipStream_t stream) {
    (void)in_sizes; (void)n_in; (void)out_size; (void)ws_size;
    const float* X      = (const float*)d_in[0];
    const int*   lens   = (const int*)d_in[1];
    const float* W_ih_f = (const float*)d_in[2];
    const float* b_ih_f = (const float*)d_in[3];
    const float* b_hh_f = (const float*)d_in[4];
    const float* W_ih_r = (const float*)d_in[5];
    const float* b_ih_r = (const float*)d_in[6];
    const float* b_hh_r = (const float*)d_in[7];
    const float* W1     = (const float*)d_in[8];
    const float* b1     = (const float*)d_in[9];
    const float* W2     = (const float*)d_in[10];
    const float* b2     = (const float*)d_in[11];
    float* out = (float*)d_out;

    char* ws = (char*)d_ws;
    unsigned short* Xb     = (unsigned short*)(ws + XB_OFF);
    unsigned short* Wp     = (unsigned short*)(ws + WP_OFF);
    float*          bias_p = (float*)(ws + BIAS_OFF);
    float*          psum   = (float*)(ws + PSUM_OFF);
    float*          pmax   = (float*)(ws + PMAX_OFF);
    float*          d1g    = (float*)(ws + D1_OFF);

    prep<<<dim3(8192 + NPACK_), 256, 0, stream>>>(
        (const float4*)X, (uint4*)Xb, lens,
        W_ih_f, b_ih_f, b_hh_f, W_ih_r, b_ih_r, b_hh_r, Wp, bias_p);
    gemm_pool<<<dim3(8192), 256, 0, stream>>>(Xb, Wp, bias_p, lens, psum, pmax);
    mlp1<<<dim3(4, 32), 256, 0, stream>>>(psum, pmax, lens, W1, b1, d1g);
    mlp2<<<dim3(B_), 256, 0, stream>>>(d1g, W2, b2, out);
}